// Round 9
// baseline (31.471 us; speedup 1.0000x reference)
//
#include <hip/hip_runtime.h>
#include <math.h>

// ---- constants from the reference ----
#define ALPHA_F   0.02f
#define BETA_F    0.015f
#define E_EX_F    0.1f
#define ZEEMAN_F  (5.79e-05f * 2.0f * 0.1f)
#define SCALE_F   ((float)(1e-11 / 6.582e-16))   // T_EVO/HBAR ~= 15193.56
#define DEPH_F    1e-4f                          // DEPH*T_EVO = 1e7*1e-11

typedef float vf2 __attribute__((ext_vector_type(2)));
typedef float vf4 __attribute__((ext_vector_type(4)));

// ---- main kernel: dense row staging + physics + per-block partials ----
__global__ __launch_bounds__(256) void main_k(
    const float* __restrict__ inp,   // (B,16)
    const float* __restrict__ sre,   // (B,2)
    const float* __restrict__ sim,   // (B,2)
    const float* __restrict__ exf,   // (Dex,3)
    const float* __restrict__ gap,   // (1,)
    float* __restrict__ out, long long out_size,
    double* __restrict__ blkB, double* __restrict__ blkD,
    float2* __restrict__ firstS, float2* __restrict__ lastS,
    int chunk, long long B, int Dex)
{
    const int t = threadIdx.x;
    const long long base = (long long)blockIdx.x * chunk;
    const int npair = chunk >> 9;            // 512-element pairs per block

    // uniform constants (uniform addresses -> scalar loads, L2-cached)
    float j0 = 0.f, j1s = 0.f, j2 = 0.f;
    for (int d = 0; d < Dex; ++d) { j0 += exf[d*3]; j1s += exf[d*3+1]; j2 += exf[d*3+2]; }
    const float invD = 1.f / (float)Dex;
    const float cx  = E_EX_F * (j0 * invD);
    const float cy  = E_EX_F * (j1s * invD);
    const float hzc = E_EX_F * (j2 * invD) + ZEEMAN_F + gap[0];
    const float Ef  = expf(-SCALE_F * DEPH_F);   // exp(damp)

    const long long psi_off = 3 * B;
    const long long mom_off = 7 * B;

    __shared__ float2 sK[512];                   // (kx,ky) per row of the pair
    __shared__ __align__(16) float sS[1536];     // both tiles' sx,sy,sz
    __shared__ float2 sCarryP[2];                // cross-pair carry (double-buffered)
    __shared__ double rr1[4], rr2[4];

    double v1 = 0.0, v2 = 0.0;
    float2 zlast = make_float2(0.f, 0.f);
    const int wid = t >> 6, lane = t & 63;

    for (int pair = 0; pair < npair; ++pair) {
        const long long pb = base + (long long)pair * 512;
        const long long i0 = pb + t;
        const long long i1 = pb + 256 + t;

        if (pair > 0) __syncthreads();           // protect sK/sS/sCarryP reuse

        // ---- dense sequential staging of input rows: 512 rows = 2048 float4 ----
        // float4 index g = q*256 + t:  row = g>>2, part = g&3.
        // For t%4==0, part==0 always -> .xy = (kx,ky) of row q*64 + t/4.
        const vf4* inpv = (const vf4*)(inp + pb * 16);
        vf4 rq0 = __builtin_nontemporal_load(inpv + 0*256 + t);
        vf4 rq1 = __builtin_nontemporal_load(inpv + 1*256 + t);
        vf4 rq2 = __builtin_nontemporal_load(inpv + 2*256 + t);
        vf4 rq3 = __builtin_nontemporal_load(inpv + 3*256 + t);
        vf4 rq4 = __builtin_nontemporal_load(inpv + 4*256 + t);
        vf4 rq5 = __builtin_nontemporal_load(inpv + 5*256 + t);
        vf4 rq6 = __builtin_nontemporal_load(inpv + 6*256 + t);
        vf4 rq7 = __builtin_nontemporal_load(inpv + 7*256 + t);

        // spinor loads (already dense 8 B/lane)
        const vf2 re0 = __builtin_nontemporal_load((const vf2*)(sre + i0 * 2));
        const vf2 re1 = __builtin_nontemporal_load((const vf2*)(sre + i1 * 2));
        const vf2 im0 = __builtin_nontemporal_load((const vf2*)(sim + i0 * 2));
        const vf2 im1 = __builtin_nontemporal_load((const vf2*)(sim + i1 * 2));

        if ((t & 3) == 0) {
            const int rb = t >> 2;               // 0..63
            sK[0*64 + rb] = make_float2(rq0.x, rq0.y);
            sK[1*64 + rb] = make_float2(rq1.x, rq1.y);
            sK[2*64 + rb] = make_float2(rq2.x, rq2.y);
            sK[3*64 + rb] = make_float2(rq3.x, rq3.y);
            sK[4*64 + rb] = make_float2(rq4.x, rq4.y);
            sK[5*64 + rb] = make_float2(rq5.x, rq5.y);
            sK[6*64 + rb] = make_float2(rq6.x, rq6.y);
            sK[7*64 + rb] = make_float2(rq7.x, rq7.y);
        }
        __syncthreads();                         // sK ready

        float zx[2], zy[2];

        #pragma unroll
        for (int j = 0; j < 2; ++j) {
            const float2 k  = sK[j * 256 + t];
            const vf2 re = j ? re1 : re0;
            const vf2 im = j ? im1 : im0;
            const long long i = j ? i1 : i0;

            // normalize spinor
            const float nrm = re.x*re.x + re.y*re.y + im.x*im.x + im.y*im.y;
            const float inv = rsqrtf(nrm);
            const float a0r = re.x*inv, a0i = im.x*inv;
            const float a1r = re.y*inv, a1i = im.y*inv;

            // effective field
            const float hx = ALPHA_F*k.y + BETA_F*k.x + cx;
            const float hy = -ALPHA_F*k.x - BETA_F*k.y + cy;

            // closed-form U = exp(damp)*[cos th - i sin th (h.sigma)/|h|]
            const float r = sqrtf(hx*hx + hy*hy + hzc*hzc);
            float s, c;
            __sincosf(SCALE_F * r, &s, &c);
            const float f  = Ef * s / fmaxf(r, 1e-37f);
            const float Ec = Ef * c;
            const float fz = f*hzc, fx = f*hx, fy = f*hy;

            const float p0r = Ec*a0r + fz*a0i - fy*a1r + fx*a1i;
            const float p0i = Ec*a0i - fz*a0r - fy*a1i - fx*a1r;
            const float p1r = Ec*a1r - fz*a1i + fy*a0r + fx*a0i;
            const float p1i = Ec*a1i + fz*a1r + fy*a0i - fx*a0r;

            // observables
            const float crr = p0r*p1r + p0i*p1i;
            const float cri = p0i*p1r - p0r*p1i;
            const float sx = 2.f*crr, sy = 2.f*cri;
            const float sz = (p0r*p0r + p0i*p0i) - (p1r*p1r + p1i*p1i);

            // NT stores: psi float4, momentum float2
            const long long o4 = psi_off + i * 4;
            if (o4 + 3 < out_size) {
                vf4 pv = {p0r, p0i, p1r, p1i};
                __builtin_nontemporal_store(pv, (vf4*)(out + o4));
            }
            const long long o2 = mom_off + i * 2;
            if (o2 + 1 < out_size) {
                vf2 mv = {k.x, k.y};
                __builtin_nontemporal_store(mv, (vf2*)(out + o2));
            }

            // stage spin triple (stride-3, conflict-free)
            const int li = j * 256 + t;
            sS[li*3 + 0] = sx; sS[li*3 + 1] = sy; sS[li*3 + 2] = sz;

            v1 += (double)(atan2f(p1i, p1r) - atan2f(p0i, p0r));
            zx[j] = sx; zy[j] = sy;
        }

        __syncthreads();                         // sS ready

        // dense out_s stores: 384 float4s (threads 0..255 + 0..127)
        const long long tb3 = pb * 3;
        if (tb3 + 1535 < out_size) {
            const int x0 = t * 4;
            vf4 a = {sS[x0], sS[x0+1], sS[x0+2], sS[x0+3]};
            __builtin_nontemporal_store(a, (vf4*)(out + tb3 + x0));
            if (t < 128) {
                const int x1 = 1024 + t * 4;
                vf4 b = {sS[x1], sS[x1+1], sS[x1+2], sS[x1+3]};
                __builtin_nontemporal_store(b, (vf4*)(out + tb3 + x1));
            }
        } else {
            for (int q = t; q < 1536; q += 256)
                if (tb3 + q < out_size) out[tb3 + q] = sS[q];
        }

        // winding diffs straight from LDS: pair (e, e+1) -> atan2(cross, dot)
        {   // j = 0: local (t, t+1)
            const float nx = sS[(t+1)*3], ny = sS[(t+1)*3 + 1];
            const float dot = nx*zx[0] + ny*zy[0];
            const float crs = zx[0]*ny - zy[0]*nx;
            v2 += (double)atan2f(crs, dot);
        }
        if (t < 255) {  // j = 1: local (256+t, 257+t)
            const float nx = sS[(257+t)*3], ny = sS[(257+t)*3 + 1];
            const float dot = nx*zx[1] + ny*zy[1];
            const float crs = zx[1]*ny - zy[1]*nx;
            v2 += (double)atan2f(crs, dot);
        }
        // cross-pair boundary: thread 0 pairs prev pair's last with its z0
        if (t == 0) {
            if (pair > 0) {
                const float2 pz = sCarryP[(pair & 1) ^ 1];
                const float dot = zx[0]*pz.x + zy[0]*pz.y;
                const float crs = pz.x*zy[0] - pz.y*zx[0];   // cross(prev, cur)
                v2 += (double)atan2f(crs, dot);
            } else {
                firstS[blockIdx.x] = make_float2(zx[0], zy[0]);
            }
        }
        if (t == 255) {
            sCarryP[pair & 1] = make_float2(zx[1], zy[1]);
            zlast = make_float2(zx[1], zy[1]);
        }
    }
    if (t == 255) lastS[blockIdx.x] = zlast;

    // deterministic block tree reduction of (v1,v2)
    for (int o = 32; o; o >>= 1) { v1 += __shfl_down(v1, o); v2 += __shfl_down(v2, o); }
    if (lane == 0) { rr1[wid] = v1; rr2[wid] = v2; }
    __syncthreads();
    if (t == 0) {
        blkB[blockIdx.x] = rr1[0] + rr1[1] + rr1[2] + rr1[3];
        blkD[blockIdx.x] = rr2[0] + rr2[1] + rr2[2] + rr2[3];
    }
}

// ---- final scalar reduction (separate kernel: implicit full visibility) ----
__global__ __launch_bounds__(256) void final_k(
    const double* __restrict__ blkB, const double* __restrict__ blkD,
    const float2* __restrict__ firstS, const float2* __restrict__ lastS,
    int nblk, long long B, float* __restrict__ out, long long out_size)
{
    const int t = threadIdx.x;
    double s1 = 0.0, s2 = 0.0;
    for (int b = t; b < nblk; b += 256) { s1 += blkB[b]; s2 += blkD[b]; }
    for (int b = t; b < nblk - 1; b += 256) {
        const float2 a = lastS[b], f2 = firstS[b + 1];
        const float dot = f2.x*a.x + f2.y*a.y;
        const float crs = a.x*f2.y - a.y*f2.x;               // cross(prev, cur)
        s2 += (double)atan2f(crs, dot);
    }
    for (int o = 32; o; o >>= 1) { s1 += __shfl_down(s1, o); s2 += __shfl_down(s2, o); }
    __shared__ double rr1[4], rr2[4];
    const int wid = t >> 6, lane = t & 63;
    if (lane == 0) { rr1[wid] = s1; rr2[wid] = s2; }
    __syncthreads();
    if (t == 0 && out_size >= 2) {
        const double sum_dph  = rr1[0] + rr1[1] + rr1[2] + rr1[3];
        const double sum_dang = rr2[0] + rr2[1] + rr2[2] + rr2[3];
        double bp = sum_dph / (double)B;
        double w = fmod(bp + (double)M_PI, 2.0 * (double)M_PI);
        if (w < 0.0) w += 2.0 * (double)M_PI;
        out[out_size - 2] = (float)(w - (double)M_PI);                          // berry_phase
        out[out_size - 1] = (float)nearbyint(sum_dang / (2.0 * (double)M_PI)); // charge
    }
}

extern "C" void kernel_launch(void* const* d_in, const int* in_sizes, int n_in,
                              void* d_out, int out_size, void* d_ws, size_t ws_size,
                              hipStream_t stream) {
    (void)n_in;
    const float* inp = (const float*)d_in[0];
    const float* sre = (const float*)d_in[1];
    const float* sim = (const float*)d_in[2];
    const float* exf = (const float*)d_in[3];
    const float* gap = (const float*)d_in[4];

    const long long B   = (long long)in_sizes[0] / 16;   // 1048576
    const int       Dex = in_sizes[3] / 3;               // 16

    // largest block count whose ws partials (32 B/block) fit; chunk multiple of 512
    int nblk = 64;
    const int cands[6] = {2048, 1024, 512, 256, 128, 64};
    for (int ci = 0; ci < 6; ++ci) {
        const int c = cands[ci];
        if (B % ((long long)c * 512) == 0 && (size_t)c * 32 + 64 <= ws_size) {
            nblk = c;
            break;
        }
    }
    const int chunk = (int)(B / nblk);   // multiple of 512

    char* ws = (char*)d_ws;
    double*  blkB   = (double*)(ws);
    double*  blkD   = (double*)(ws + (size_t)nblk * 8);
    float2*  firstS = (float2*)(ws + (size_t)nblk * 16);
    float2*  lastS  = (float2*)(ws + (size_t)nblk * 24);

    main_k<<<nblk, 256, 0, stream>>>(inp, sre, sim, exf, gap,
                                     (float*)d_out, (long long)out_size,
                                     blkB, blkD, firstS, lastS,
                                     chunk, B, Dex);
    final_k<<<1, 256, 0, stream>>>(blkB, blkD, firstS, lastS,
                                   nblk, B, (float*)d_out, (long long)out_size);
}

// Round 10
// 28.018 us; speedup vs baseline: 1.1232x; 1.1232x over previous
//
#include <hip/hip_runtime.h>
#include <math.h>

// ---- constants from the reference ----
#define ALPHA_F   0.02f
#define BETA_F    0.015f
#define E_EX_F    0.1f
#define ZEEMAN_F  (5.79e-05f * 2.0f * 0.1f)
#define SCALE_F   ((float)(1e-11 / 6.582e-16))   // T_EVO/HBAR ~= 15193.56
#define DEPH_F    1e-4f                          // DEPH*T_EVO = 1e7*1e-11

typedef float vf2 __attribute__((ext_vector_type(2)));
typedef float vf4 __attribute__((ext_vector_type(4)));

// ---- main kernel: physics + per-block partials (no device-scope fences) ----
__global__ __launch_bounds__(256) void main_k(
    const float* __restrict__ inp,   // (B,16)
    const float* __restrict__ sre,   // (B,2)
    const float* __restrict__ sim,   // (B,2)
    const float* __restrict__ exf,   // (Dex,3)
    const float* __restrict__ gap,   // (1,)
    float* __restrict__ out, long long out_size,
    double* __restrict__ blkB, double* __restrict__ blkD,
    int chunk, long long B, int Dex)
{
    const int t = threadIdx.x;
    const long long base = (long long)blockIdx.x * chunk;
    const int ntile = chunk >> 8;

    // issue first tile's loads immediately (non-temporal: pure streaming, no reuse)
    vf2 k_c  = __builtin_nontemporal_load((const vf2*)(inp + (base + t) * 16));
    vf2 re_c = __builtin_nontemporal_load((const vf2*)(sre + (base + t) * 2));
    vf2 im_c = __builtin_nontemporal_load((const vf2*)(sim + (base + t) * 2));

    // uniform constants (uniform addresses -> scalar loads, L2-cached)
    float j0 = 0.f, j1 = 0.f, j2 = 0.f;
    for (int d = 0; d < Dex; ++d) { j0 += exf[d*3]; j1 += exf[d*3+1]; j2 += exf[d*3+2]; }
    const float invD = 1.f / (float)Dex;
    const float cx  = E_EX_F * (j0 * invD);
    const float cy  = E_EX_F * (j1 * invD);
    const float hzc = E_EX_F * (j2 * invD) + ZEEMAN_F + gap[0];
    const float Ef  = expf(-SCALE_F * DEPH_F);     // exp(damp)

    const long long psi_off = 3 * B;
    const long long mom_off = 7 * B;

    __shared__ float  sS[768];       // staged sx,sy,sz for dense stores
    __shared__ float2 sFirst[4];     // lane-0 z of each wave (wave-boundary pairs)
    __shared__ float2 sCarry[2];     // t==255 z, double-buffered across tiles
    __shared__ double rr1[4], rr2[4];

    double v1 = 0.0, v2 = 0.0;
    const int wid = t >> 6, lane = t & 63;

    for (int tile = 0; tile < ntile; ++tile) {
        const long long icur = base + (long long)tile * 256 + t;
        const vf2 k = k_c, re = re_c, im = im_c;

        // prefetch next tile (keeps 3 more loads in flight during compute)
        if (tile + 1 < ntile) {
            const long long inx = icur + 256;
            k_c  = __builtin_nontemporal_load((const vf2*)(inp + inx * 16));
            re_c = __builtin_nontemporal_load((const vf2*)(sre + inx * 2));
            im_c = __builtin_nontemporal_load((const vf2*)(sim + inx * 2));
        }

        // normalize spinor
        const float nrm = re.x*re.x + re.y*re.y + im.x*im.x + im.y*im.y;
        const float inv = rsqrtf(nrm);
        const float a0r = re.x*inv, a0i = im.x*inv;
        const float a1r = re.y*inv, a1i = im.y*inv;

        // effective field
        const float hx = ALPHA_F*k.y + BETA_F*k.x + cx;
        const float hy = -ALPHA_F*k.x - BETA_F*k.y + cy;

        // closed-form U = exp(damp)*[cos th - i sin th (h.sigma)/|h|]
        const float r = sqrtf(hx*hx + hy*hy + hzc*hzc);
        float s, c;
        __sincosf(SCALE_F * r, &s, &c);
        const float f  = Ef * s / fmaxf(r, 1e-37f);
        const float Ec = Ef * c;
        const float fz = f*hzc, fx = f*hx, fy = f*hy;

        const float p0r = Ec*a0r + fz*a0i - fy*a1r + fx*a1i;
        const float p0i = Ec*a0i - fz*a0r - fy*a1i - fx*a1r;
        const float p1r = Ec*a1r - fz*a1i + fy*a0r + fx*a0i;
        const float p1i = Ec*a1i + fz*a1r + fy*a0i - fx*a0r;

        // observables
        const float crr = p0r*p1r + p0i*p1i;     // Re(p0*conj(p1))
        const float cri = p0i*p1r - p0r*p1i;     // Im(p0*conj(p1))
        const float sx = 2.f*crr, sy = 2.f*cri;
        const float sz = (p0r*p0r + p0i*p0i) - (p1r*p1r + p1i*p1i);

        // dense NT stores: psi (float4/lane), momentum (float2/lane)
        const long long o4 = psi_off + icur * 4;
        if (o4 + 3 < out_size) {
            vf4 pv = {p0r, p0i, p1r, p1i};
            __builtin_nontemporal_store(pv, (vf4*)(out + o4));
        }
        const long long o2 = mom_off + icur * 2;
        if (o2 + 1 < out_size) {
            vf2 mv = {k.x, k.y};
            __builtin_nontemporal_store(mv, (vf2*)(out + o2));
        }

        // stage spin triple for dense full-line stores (stride-3: gcd(3,32)=1, conflict-free)
        sS[t*3 + 0] = sx; sS[t*3 + 1] = sy; sS[t*3 + 2] = sz;
        if (lane == 0)  sFirst[wid] = make_float2(sx, sy);
        if (t == 255)   sCarry[tile & 1] = make_float2(sx, sy);

        // in-wave neighbor via shuffle
        const float znx = __shfl_down(sx, 1);
        const float zny = __shfl_down(sy, 1);
        __syncthreads();

        // out_s: three dense wave-segments (full 64B lines), non-temporal
        const long long tb3 = (base + (long long)tile * 256) * 3;
        if (tb3 + 767 < out_size) {
            __builtin_nontemporal_store(sS[t],       out + tb3 + t);
            __builtin_nontemporal_store(sS[256 + t], out + tb3 + 256 + t);
            __builtin_nontemporal_store(sS[512 + t], out + tb3 + 512 + t);
        } else {
            if (tb3 + t < out_size)       out[tb3 + t]       = sS[t];
            if (tb3 + 256 + t < out_size) out[tb3 + 256 + t] = sS[256 + t];
            if (tb3 + 512 + t < out_size) out[tb3 + 512 + t] = sS[512 + t];
        }

        // berry phase term
        v1 += (double)(atan2f(p1i, p1r) - atan2f(p0i, p0r));

        // winding diffs: wrap_pi(ang[i+1]-ang[i]) == atan2(cross(cur,next), dot)
        if (lane < 63) {
            const float dot = znx*sx + zny*sy;
            const float crs = sx*zny - sy*znx;
            v2 += (double)atan2f(crs, dot);
        } else if (wid < 3) {
            const float2 nf = sFirst[wid + 1];
            const float dot = nf.x*sx + nf.y*sy;
            const float crs = sx*nf.y - sy*nf.x;
            v2 += (double)atan2f(crs, dot);
        }
        if (t == 0) {
            if (tile > 0) {
                const float2 pz = sCarry[(tile & 1) ^ 1];   // prev tile's last
                const float dot = sx*pz.x + sy*pz.y;
                const float crs = pz.x*sy - pz.y*sx;        // cross(prev, cur)
                v2 += (double)atan2f(crs, dot);
            } else if (blockIdx.x > 0) {
                // cross-BLOCK boundary: recompute element base-1 locally
                // (removes firstS/lastS arrays + final_k boundary pass)
                const long long ip = base - 1;
                const float2 kp  = *reinterpret_cast<const float2*>(inp + ip * 16);
                const float2 rep = *reinterpret_cast<const float2*>(sre + ip * 2);
                const float2 imp = *reinterpret_cast<const float2*>(sim + ip * 2);
                const float nrmp = rep.x*rep.x + rep.y*rep.y + imp.x*imp.x + imp.y*imp.y;
                const float invp = rsqrtf(nrmp);
                const float b0r = rep.x*invp, b0i = imp.x*invp;
                const float b1r = rep.y*invp, b1i = imp.y*invp;
                const float hxp = ALPHA_F*kp.y + BETA_F*kp.x + cx;
                const float hyp = -ALPHA_F*kp.x - BETA_F*kp.y + cy;
                const float rp  = sqrtf(hxp*hxp + hyp*hyp + hzc*hzc);
                float sp, cp;
                __sincosf(SCALE_F * rp, &sp, &cp);
                const float fp  = Ef * sp / fmaxf(rp, 1e-37f);
                const float Ecp = Ef * cp;
                const float fzp = fp*hzc, fxp = fp*hxp, fyp = fp*hyp;
                const float q0r = Ecp*b0r + fzp*b0i - fyp*b1r + fxp*b1i;
                const float q0i = Ecp*b0i - fzp*b0r - fyp*b1i - fxp*b1r;
                const float q1r = Ecp*b1r - fzp*b1i + fyp*b0r + fxp*b0i;
                const float q1i = Ecp*b1i + fzp*b1r + fyp*b0i - fxp*b0r;
                const float pzx = 2.f*(q0r*q1r + q0i*q1i);
                const float pzy = 2.f*(q0i*q1r - q0r*q1i);
                const float dot = sx*pzx + sy*pzy;
                const float crs = pzx*sy - pzy*sx;          // cross(prev, cur)
                v2 += (double)atan2f(crs, dot);
            }
        }
        __syncthreads();   // protect sS/sFirst reuse next tile
    }

    // deterministic block tree reduction of (v1,v2)
    for (int o = 32; o; o >>= 1) { v1 += __shfl_down(v1, o); v2 += __shfl_down(v2, o); }
    if (lane == 0) { rr1[wid] = v1; rr2[wid] = v2; }
    __syncthreads();
    if (t == 0) {
        blkB[blockIdx.x] = rr1[0] + rr1[1] + rr1[2] + rr1[3];
        blkD[blockIdx.x] = rr2[0] + rr2[1] + rr2[2] + rr2[3];
    }
}

// ---- final scalar reduction (separate kernel: implicit full visibility) ----
__global__ __launch_bounds__(256) void final_k(
    const double* __restrict__ blkB, const double* __restrict__ blkD,
    int nblk, long long B, float* __restrict__ out, long long out_size)
{
    const int t = threadIdx.x;
    double s1 = 0.0, s2 = 0.0;
    for (int b = t; b < nblk; b += 256) { s1 += blkB[b]; s2 += blkD[b]; }
    for (int o = 32; o; o >>= 1) { s1 += __shfl_down(s1, o); s2 += __shfl_down(s2, o); }
    __shared__ double rr1[4], rr2[4];
    const int wid = t >> 6, lane = t & 63;
    if (lane == 0) { rr1[wid] = s1; rr2[wid] = s2; }
    __syncthreads();
    if (t == 0 && out_size >= 2) {
        const double sum_dph  = rr1[0] + rr1[1] + rr1[2] + rr1[3];
        const double sum_dang = rr2[0] + rr2[1] + rr2[2] + rr2[3];
        double bp = sum_dph / (double)B;
        double w = fmod(bp + (double)M_PI, 2.0 * (double)M_PI);
        if (w < 0.0) w += 2.0 * (double)M_PI;
        out[out_size - 2] = (float)(w - (double)M_PI);                          // berry_phase
        out[out_size - 1] = (float)nearbyint(sum_dang / (2.0 * (double)M_PI)); // charge
    }
}

extern "C" void kernel_launch(void* const* d_in, const int* in_sizes, int n_in,
                              void* d_out, int out_size, void* d_ws, size_t ws_size,
                              hipStream_t stream) {
    (void)n_in;
    const float* inp = (const float*)d_in[0];
    const float* sre = (const float*)d_in[1];
    const float* sim = (const float*)d_in[2];
    const float* exf = (const float*)d_in[3];
    const float* gap = (const float*)d_in[4];

    const long long B   = (long long)in_sizes[0] / 16;   // 1048576
    const int       Dex = in_sizes[3] / 3;               // 16

    // largest block count whose ws partials (16 B/block) fit
    // prefer 2048 = exactly 8 blocks/CU (one full residency round)
    int nblk = 64;
    const int cands[6] = {2048, 1024, 512, 256, 128, 64};
    for (int ci = 0; ci < 6; ++ci) {
        const int c = cands[ci];
        if (B % ((long long)c * 256) == 0 && (size_t)c * 16 + 64 <= ws_size) {
            nblk = c;
            break;
        }
    }
    const int chunk = (int)(B / nblk);   // multiple of 256

    char* ws = (char*)d_ws;
    double* blkB = (double*)(ws);
    double* blkD = (double*)(ws + (size_t)nblk * 8);

    main_k<<<nblk, 256, 0, stream>>>(inp, sre, sim, exf, gap,
                                     (float*)d_out, (long long)out_size,
                                     blkB, blkD, chunk, B, Dex);
    final_k<<<1, 256, 0, stream>>>(blkB, blkD, nblk, B,
                                   (float*)d_out, (long long)out_size);
}